// Round 5
// baseline (622.192 us; speedup 1.0000x reference)
//
#include <hip/hip_runtime.h>
#include <math.h>

#define NF   128   // n_features
#define DE   64    // d_embed
#define GS   5     // grid_size
#define SO   3     // spline_order
#define FG   10    // fourier_gridsize
#define NG   12    // grid cols = GS + 2*SO + 1
#define NB0  11    // order-0 bases
#define NBF  8     // final bases = GS + SO
#define WREC 32    // floats per packed record (weights W and scalars S)
#define BPW  128   // b's per wave in kan_dot

// W[(n*64+d)*32]:  [0]=base_w, [1]=fourier_bias, [2..9]=spline_w*scaler,
//                  [10..19]=c_cos, [20..29]=c_sin, [30,31]=pad
// S[(b*128+n)*32]: [0]=silu(x), [1]=1.0, [2..9]=bases, [10..19]=cos, [20..29]=sin
// => out[b,n,d] = sum_j S[b,n,j] * W[n,d,j]   (j = 0..29)
// INV[n*32+j]: j 0..10 = 1/(g[j+1]-g[j]); 11..20 = 1/(g[j+2]-g[j]); 21..29 = 1/(g[j+3]-g[j])

__global__ __launch_bounds__(256)
void kan_prep(const float* __restrict__ grid,
              const float* __restrict__ bw, const float* __restrict__ sw,
              const float* __restrict__ ss, const float* __restrict__ fc,
              const float* __restrict__ fb,
              float* __restrict__ W, float* __restrict__ INV) {
  int idx = blockIdx.x * blockDim.x + threadIdx.x;
  if (idx >= NF * DE) return;
  int n = idx >> 6, d = idx & 63;
  (void)d;
  float* w = W + (size_t)idx * WREC;
  w[0] = bw[idx];
  w[1] = fb[idx];
  float s = ss[idx];
  const float* swp = sw + (size_t)idx * NBF;
#pragma unroll
  for (int i = 0; i < NBF; ++i) w[2 + i] = swp[i] * s;
  const float* f0 = fc + (size_t)idx * FG;
  const float* f1 = fc + (size_t)(NF * DE + idx) * FG;
#pragma unroll
  for (int g = 0; g < FG; ++g) { w[10 + g] = f0[g]; w[20 + g] = f1[g]; }
  w[30] = 0.f; w[31] = 0.f;
  if (d == 0) {
    const float* g_ = grid + n * NG;
    float* iv = INV + n * 32;
    int o = 0;
#pragma unroll
    for (int k = 1; k <= SO; ++k)
      for (int j = 0; j + k < NG; ++j)
        iv[o++] = 1.0f / (g_[j + k] - g_[j]);
    iv[30] = 0.f; iv[31] = 0.f;
  }
}

// k1: per-(b,n) scalar records -> S (134 MB, L3-resident until k2 reads it)
__global__ __launch_bounds__(256)
void kan_scal(const float* __restrict__ x, const float* __restrict__ grid,
              const float* __restrict__ INV, float* __restrict__ S, int B) {
  const int n = blockIdx.x;
  const int b = blockIdx.y * 256 + threadIdx.x;
  if (b >= B) return;

  const float xv = x[(size_t)b * NF + n];

  float g[NG];
#pragma unroll
  for (int j = 0; j < NG; ++j) g[j] = grid[n * NG + j];

  const float sil = xv / (1.0f + expf(-xv));

  float bs[NB0];
#pragma unroll
  for (int j = 0; j < NB0; ++j)
    bs[j] = (xv >= g[j] && xv < g[j + 1]) ? 1.0f : 0.0f;

  const float* iv = INV + n * 32;
  const float* iv1 = iv;        // 11 entries: 1/(g[j+1]-g[j])
  const float* iv2 = iv + 11;   // 10 entries: 1/(g[j+2]-g[j])
  const float* iv3 = iv + 21;   //  9 entries: 1/(g[j+3]-g[j])
#pragma unroll
  for (int j = 0; j < 10; ++j) {
    float left  = (xv - g[j]) * iv1[j];
    float right = (g[j + 2] - xv) * iv1[j + 1];
    bs[j] = left * bs[j] + right * bs[j + 1];
  }
#pragma unroll
  for (int j = 0; j < 9; ++j) {
    float left  = (xv - g[j]) * iv2[j];
    float right = (g[j + 3] - xv) * iv2[j + 1];
    bs[j] = left * bs[j] + right * bs[j + 1];
  }
#pragma unroll
  for (int j = 0; j < 8; ++j) {
    float left  = (xv - g[j]) * iv3[j];
    float right = (g[j + 4] - xv) * iv3[j + 1];
    bs[j] = left * bs[j] + right * bs[j + 1];
  }

  float cs[FG], sn[FG];
  float s1, c1;
  sincosf(xv, &s1, &c1);
  cs[0] = c1; sn[0] = s1;
#pragma unroll
  for (int gi = 1; gi < FG; ++gi) {
    float cp = cs[gi - 1], sp = sn[gi - 1];
    cs[gi] = cp * c1 - sp * s1;
    sn[gi] = sp * c1 + cp * s1;
  }

  float r[WREC];
  r[0] = sil; r[1] = 1.0f;
#pragma unroll
  for (int j = 0; j < NBF; ++j) r[2 + j] = bs[j];
#pragma unroll
  for (int gi = 0; gi < FG; ++gi) { r[10 + gi] = cs[gi]; r[20 + gi] = sn[gi]; }
  r[30] = 0.f; r[31] = 0.f;

  float4* sp4 = reinterpret_cast<float4*>(S + ((size_t)b * NF + n) * WREC);
#pragma unroll
  for (int q = 0; q < 8; ++q)
    sp4[q] = make_float4(r[q * 4 + 0], r[q * 4 + 1], r[q * 4 + 2], r[q * 4 + 3]);
}

// k2: lane=d, weights VGPR-resident, scalars via wave-uniform s_load, coalesced stores
__global__ __launch_bounds__(256, 8)
void kan_dot(const float* __restrict__ W, const float* __restrict__ S,
             float* __restrict__ out, int B) {
  const int n = blockIdx.x;
  const int wv = __builtin_amdgcn_readfirstlane(threadIdx.x >> 6);  // force SGPR
  const int lane = threadIdx.x & 63;
  const int bstart = (blockIdx.y * 4 + wv) * BPW;
  if (bstart >= B) return;
  const int nb = (B - bstart < BPW) ? (B - bstart) : BPW;

  // this lane's d-record: 32 VGPRs, loaded once
  float wr[WREC];
  const float4* wq = reinterpret_cast<const float4*>(W + ((size_t)n * DE + lane) * WREC);
#pragma unroll
  for (int q = 0; q < 8; ++q) {
    float4 t = wq[q];
    wr[q * 4 + 0] = t.x; wr[q * 4 + 1] = t.y; wr[q * 4 + 2] = t.z; wr[q * 4 + 3] = t.w;
  }

  const float* sp = S + ((size_t)bstart * NF + n) * WREC;          // wave-uniform
  float* op = out + ((size_t)bstart * NF + n) * DE + lane;

  for (int i = 0; i < nb; ++i) {
    float a0 = 0.f, a1 = 0.f, a2 = 0.f, a3 = 0.f;                  // 4 chains: break dep-latency
#pragma unroll
    for (int j = 0; j < 28; j += 4) {
      a0 = fmaf(sp[j + 0], wr[j + 0], a0);
      a1 = fmaf(sp[j + 1], wr[j + 1], a1);
      a2 = fmaf(sp[j + 2], wr[j + 2], a2);
      a3 = fmaf(sp[j + 3], wr[j + 3], a3);
    }
    a0 = fmaf(sp[28], wr[28], a0);
    a1 = fmaf(sp[29], wr[29], a1);
    *op = (a0 + a1) + (a2 + a3);
    sp += (size_t)NF * WREC;
    op += (size_t)NF * DE;
  }
}

// fallback monolith (no workspace): correctness safety net
__global__ __launch_bounds__(256)
void kan_mono(const float* __restrict__ x, const float* __restrict__ grid,
              const float* __restrict__ bw, const float* __restrict__ sw,
              const float* __restrict__ ss, const float* __restrict__ fc,
              const float* __restrict__ fb, float* __restrict__ out, int B) {
  const int n = blockIdx.x;
  const int wv = threadIdx.x >> 6;
  const int lane = threadIdx.x & 63;
  const int b = ((blockIdx.y * 4 + wv) << 6) + lane;
  if (b >= B) return;
  const float xv = x[(size_t)b * NF + n];
  float g[NG];
#pragma unroll
  for (int j = 0; j < NG; ++j) g[j] = grid[n * NG + j];
  const float sil = xv / (1.0f + expf(-xv));
  float bs[NB0];
#pragma unroll
  for (int j = 0; j < NB0; ++j)
    bs[j] = (xv >= g[j] && xv < g[j + 1]) ? 1.0f : 0.0f;
#pragma unroll
  for (int k = 1; k <= SO; ++k) {
    for (int j = 0; j < NB0 - k; ++j) {
      float left  = (xv - g[j]) / (g[j + k] - g[j]);
      float right = (g[j + k + 1] - xv) / (g[j + k + 1] - g[j + 1]);
      bs[j] = left * bs[j] + right * bs[j + 1];
    }
  }
  float cs[FG], sn[FG];
  float s1, c1;
  sincosf(xv, &s1, &c1);
  cs[0] = c1; sn[0] = s1;
#pragma unroll
  for (int gi = 1; gi < FG; ++gi) {
    float cp = cs[gi - 1], sp = sn[gi - 1];
    cs[gi] = cp * c1 - sp * s1;
    sn[gi] = sp * c1 + cp * s1;
  }
  const float* bwp = bw + n * DE;
  const float* fbp = fb + n * DE;
  const float* ssp = ss + n * DE;
  const float* swp = sw + (size_t)n * DE * NBF;
  const float* f0  = fc + (size_t)n * DE * FG;
  const float* f1  = fc + (size_t)(NF + n) * DE * FG;
  float4* outp = reinterpret_cast<float4*>(out + ((size_t)b * NF + n) * DE);
  for (int d4 = 0; d4 < DE / 4; ++d4) {
    float4 o;
#pragma unroll
    for (int q = 0; q < 4; ++q) {
      int d = d4 * 4 + q;
      float a = fmaf(sil, bwp[d], fbp[d]);
      float scl = ssp[d];
#pragma unroll
      for (int i = 0; i < NBF; ++i) a = fmaf(bs[i] * scl, swp[d * NBF + i], a);
#pragma unroll
      for (int gi = 0; gi < FG; ++gi) a = fmaf(cs[gi], f0[d * FG + gi], a);
#pragma unroll
      for (int gi = 0; gi < FG; ++gi) a = fmaf(sn[gi], f1[d * FG + gi], a);
      (&o.x)[q] = a;
    }
    outp[d4] = o;
  }
}

extern "C" void kernel_launch(void* const* d_in, const int* in_sizes, int n_in,
                              void* d_out, int out_size, void* d_ws, size_t ws_size,
                              hipStream_t stream) {
  const float* x    = (const float*)d_in[0];
  const float* grid = (const float*)d_in[1];
  const float* bw   = (const float*)d_in[2];
  const float* sw   = (const float*)d_in[3];
  const float* ss   = (const float*)d_in[4];
  const float* fc   = (const float*)d_in[5];
  const float* fb   = (const float*)d_in[6];
  float* out = (float*)d_out;

  const int B = in_sizes[0] / NF;  // 8192
  const size_t wBytes = (size_t)NF * DE * WREC * sizeof(float);   // 1 MB
  const size_t iBytes = (size_t)NF * 32 * sizeof(float);          // 16 KB
  const size_t sBytes = (size_t)B * NF * WREC * sizeof(float);    // 134 MB @ B=8192
  const size_t need = wBytes + iBytes + sBytes;

  if (ws_size >= need) {
    float* W   = (float*)d_ws;
    float* INV = W + (size_t)NF * DE * WREC;
    float* S   = INV + (size_t)NF * 32;
    kan_prep<<<(NF * DE + 255) / 256, 256, 0, stream>>>(grid, bw, sw, ss, fc, fb, W, INV);
    dim3 g1(NF, (unsigned)((B + 255) / 256));
    kan_scal<<<g1, 256, 0, stream>>>(x, grid, INV, S, B);
    dim3 g2(NF, (unsigned)((B + BPW * 4 - 1) / (BPW * 4)));
    kan_dot<<<g2, 256, 0, stream>>>(W, S, out, B);
  } else {
    dim3 mg(NF, (unsigned)((B + 255) / 256));
    kan_mono<<<mg, 256, 0, stream>>>(x, grid, bw, sw, ss, fc, fb, out, B);
  }
}

// Round 6
// 378.319 us; speedup vs baseline: 1.6446x; 1.6446x over previous
//
#include <hip/hip_runtime.h>
#include <math.h>

#define NF   128   // n_features
#define DE   64    // d_embed
#define GS   5     // grid_size
#define SO   3     // spline_order
#define FG   10    // fourier_gridsize
#define NG   12    // grid cols = GS + 2*SO + 1
#define NB0  11    // order-0 bases
#define NBF  8     // final bases = GS + SO
#define WREC 32    // floats per packed weight record

// W[(n*64+d)*32]: [0]=base_w, [1]=fourier_bias, [2..9]=spline_w*scaler,
//                 [10..19]=c_cos, [20..29]=c_sin, [30,31]=pad
// INV[n*32+j]: j 0..10 = 1/(g[j+1]-g[j]); 11..20 = 1/(g[j+2]-g[j]); 21..29 = 1/(g[j+3]-g[j])
// sv[29] per-lane scalars: [0]=silu, [1..8]=bases, [9..18]=cos, [19..28]=sin; bias has implicit 1.0

__global__ __launch_bounds__(256)
void kan_prep(const float* __restrict__ grid,
              const float* __restrict__ bw, const float* __restrict__ sw,
              const float* __restrict__ ss, const float* __restrict__ fc,
              const float* __restrict__ fb,
              float* __restrict__ W, float* __restrict__ INV) {
  int idx = blockIdx.x * blockDim.x + threadIdx.x;
  if (idx >= NF * DE) return;
  int n = idx >> 6, d = idx & 63;
  (void)d;
  float* w = W + (size_t)idx * WREC;
  w[0] = bw[idx];
  w[1] = fb[idx];
  float s = ss[idx];
  const float* swp = sw + (size_t)idx * NBF;
#pragma unroll
  for (int i = 0; i < NBF; ++i) w[2 + i] = swp[i] * s;
  const float* f0 = fc + (size_t)idx * FG;
  const float* f1 = fc + (size_t)(NF * DE + idx) * FG;
#pragma unroll
  for (int g = 0; g < FG; ++g) { w[10 + g] = f0[g]; w[20 + g] = f1[g]; }
  w[30] = 0.f; w[31] = 0.f;
  if (d == 0) {
    const float* g_ = grid + n * NG;
    float* iv = INV + n * 32;
    int o = 0;
#pragma unroll
    for (int k = 1; k <= SO; ++k)
      for (int j = 0; j + k < NG; ++j)
        iv[o++] = 1.0f / (g_[j + k] - g_[j]);
    iv[30] = 0.f; iv[31] = 0.f;
  }
}

__device__ __forceinline__ float bcast_lane(float v, int src) {
  return __int_as_float(__builtin_amdgcn_readlane(__float_as_int(v), src));
}

// Fused: wave owns (n, 64 consecutive b). Phase A: lane=b computes its 29 scalars.
// Phase B: lane=d holds W[n,d,*] in VGPRs; per b, readlane-broadcast scalars -> SGPR,
// v_fmac(SGPR,VGPR), fully-coalesced 256B store per b. No LDS, no scalar streaming.
__global__ __launch_bounds__(256)
void kan_fused(const float* __restrict__ x, const float* __restrict__ grid,
               const float* __restrict__ INV, const float* __restrict__ W,
               float* __restrict__ out, int B) {
  const int n = blockIdx.x;
  const int lane = threadIdx.x & 63;
  const int wv = threadIdx.x >> 6;
  const int b0 = blockIdx.y * 256 + wv * 64;     // wave's b-base
  if (b0 >= B) return;
  const int myb = b0 + lane;

  // ---- phase A: scalars for my own b (lane = b) ----
  float xv = (myb < B) ? x[(size_t)myb * NF + n] : 0.0f;

  float g[NG];
#pragma unroll
  for (int j = 0; j < NG; ++j) g[j] = grid[n * NG + j];  // uniform -> scalar, one-time

  float sv[29];
  sv[0] = xv / (1.0f + expf(-xv));                       // silu

  float bs[NB0];
#pragma unroll
  for (int j = 0; j < NB0; ++j)
    bs[j] = (xv >= g[j] && xv < g[j + 1]) ? 1.0f : 0.0f;

  const float* iv = INV + n * 32;                        // uniform one-time s_load
  const float* iv1 = iv;
  const float* iv2 = iv + 11;
  const float* iv3 = iv + 21;
#pragma unroll
  for (int j = 0; j < 10; ++j) {
    float left  = (xv - g[j]) * iv1[j];
    float right = (g[j + 2] - xv) * iv1[j + 1];
    bs[j] = left * bs[j] + right * bs[j + 1];
  }
#pragma unroll
  for (int j = 0; j < 9; ++j) {
    float left  = (xv - g[j]) * iv2[j];
    float right = (g[j + 3] - xv) * iv2[j + 1];
    bs[j] = left * bs[j] + right * bs[j + 1];
  }
#pragma unroll
  for (int j = 0; j < 8; ++j) {
    float left  = (xv - g[j]) * iv3[j];
    float right = (g[j + 4] - xv) * iv3[j + 1];
    bs[j] = left * bs[j] + right * bs[j + 1];
  }
#pragma unroll
  for (int j = 0; j < NBF; ++j) sv[1 + j] = bs[j];

  {
    float s1, c1;
    sincosf(xv, &s1, &c1);
    sv[9] = c1; sv[19] = s1;
#pragma unroll
    for (int gi = 1; gi < FG; ++gi) {
      float cp = sv[9 + gi - 1], sp = sv[19 + gi - 1];
      sv[9 + gi]  = cp * c1 - sp * s1;
      sv[19 + gi] = sp * c1 + cp * s1;
    }
  }

  // ---- phase B: lane = d. Load my d-record into VGPRs (coalesced, once). ----
  float wr[30];
  {
    const float4* wq = reinterpret_cast<const float4*>(W + ((size_t)n * DE + lane) * WREC);
#pragma unroll
    for (int q = 0; q < 7; ++q) {
      float4 t = wq[q];
      wr[q * 4 + 0] = t.x; wr[q * 4 + 1] = t.y; wr[q * 4 + 2] = t.z; wr[q * 4 + 3] = t.w;
    }
    float2 t7 = reinterpret_cast<const float2*>(wq)[14];   // floats 28,29
    wr[28] = t7.x; wr[29] = t7.y;
  }

  float* op = out + ((size_t)b0 * NF + n) * DE + lane;
  const int nb = (B - b0 < 64) ? (B - b0) : 64;

#pragma unroll 4
  for (int bi = 0; bi < nb; ++bi) {
    // broadcast scalars of b0+bi from lane bi -> SGPRs; two fmac chains for ILP
    float a0 = wr[1];                                     // fourier bias * 1.0
    float a1 = bcast_lane(sv[0], bi) * wr[0];             // silu * base_w
#pragma unroll
    for (int j = 0; j < NBF; j += 2) {                    // spline: wr[2..9]
      a0 = fmaf(bcast_lane(sv[1 + j],     bi), wr[2 + j],     a0);
      a1 = fmaf(bcast_lane(sv[1 + j + 1], bi), wr[2 + j + 1], a1);
    }
#pragma unroll
    for (int gi = 0; gi < FG; gi += 2) {                  // cos: wr[10..19]
      a0 = fmaf(bcast_lane(sv[9 + gi],     bi), wr[10 + gi],     a0);
      a1 = fmaf(bcast_lane(sv[9 + gi + 1], bi), wr[10 + gi + 1], a1);
    }
#pragma unroll
    for (int gi = 0; gi < FG; gi += 2) {                  // sin: wr[20..29]
      a0 = fmaf(bcast_lane(sv[19 + gi],     bi), wr[20 + gi],     a0);
      a1 = fmaf(bcast_lane(sv[19 + gi + 1], bi), wr[20 + gi + 1], a1);
    }
    op[(size_t)bi * NF * DE] = a0 + a1;                   // 256 B coalesced per wave
  }
}

// fallback monolith (no workspace): correctness safety net
__global__ __launch_bounds__(256)
void kan_mono(const float* __restrict__ x, const float* __restrict__ grid,
              const float* __restrict__ bw, const float* __restrict__ sw,
              const float* __restrict__ ss, const float* __restrict__ fc,
              const float* __restrict__ fb, float* __restrict__ out, int B) {
  const int n = blockIdx.x;
  const int wv = threadIdx.x >> 6;
  const int lane = threadIdx.x & 63;
  const int b = ((blockIdx.y * 4 + wv) << 6) + lane;
  if (b >= B) return;
  const float xv = x[(size_t)b * NF + n];
  float g[NG];
#pragma unroll
  for (int j = 0; j < NG; ++j) g[j] = grid[n * NG + j];
  const float sil = xv / (1.0f + expf(-xv));
  float bs[NB0];
#pragma unroll
  for (int j = 0; j < NB0; ++j)
    bs[j] = (xv >= g[j] && xv < g[j + 1]) ? 1.0f : 0.0f;
#pragma unroll
  for (int k = 1; k <= SO; ++k) {
    for (int j = 0; j < NB0 - k; ++j) {
      float left  = (xv - g[j]) / (g[j + k] - g[j]);
      float right = (g[j + k + 1] - xv) / (g[j + k + 1] - g[j + 1]);
      bs[j] = left * bs[j] + right * bs[j + 1];
    }
  }
  float cs[FG], sn[FG];
  float s1, c1;
  sincosf(xv, &s1, &c1);
  cs[0] = c1; sn[0] = s1;
#pragma unroll
  for (int gi = 1; gi < FG; ++gi) {
    float cp = cs[gi - 1], sp = sn[gi - 1];
    cs[gi] = cp * c1 - sp * s1;
    sn[gi] = sp * c1 + cp * s1;
  }
  const float* bwp = bw + n * DE;
  const float* fbp = fb + n * DE;
  const float* ssp = ss + n * DE;
  const float* swp = sw + (size_t)n * DE * NBF;
  const float* f0  = fc + (size_t)n * DE * FG;
  const float* f1  = fc + (size_t)(NF + n) * DE * FG;
  float4* outp = reinterpret_cast<float4*>(out + ((size_t)b * NF + n) * DE);
  for (int d4 = 0; d4 < DE / 4; ++d4) {
    float4 o;
#pragma unroll
    for (int q = 0; q < 4; ++q) {
      int d = d4 * 4 + q;
      float a = fmaf(sil, bwp[d], fbp[d]);
      float scl = ssp[d];
#pragma unroll
      for (int i = 0; i < NBF; ++i) a = fmaf(bs[i] * scl, swp[d * NBF + i], a);
#pragma unroll
      for (int gi = 0; gi < FG; ++gi) a = fmaf(cs[gi], f0[d * FG + gi], a);
#pragma unroll
      for (int gi = 0; gi < FG; ++gi) a = fmaf(sn[gi], f1[d * FG + gi], a);
      (&o.x)[q] = a;
    }
    outp[d4] = o;
  }
}

extern "C" void kernel_launch(void* const* d_in, const int* in_sizes, int n_in,
                              void* d_out, int out_size, void* d_ws, size_t ws_size,
                              hipStream_t stream) {
  const float* x    = (const float*)d_in[0];
  const float* grid = (const float*)d_in[1];
  const float* bw   = (const float*)d_in[2];
  const float* sw   = (const float*)d_in[3];
  const float* ss   = (const float*)d_in[4];
  const float* fc   = (const float*)d_in[5];
  const float* fb   = (const float*)d_in[6];
  float* out = (float*)d_out;

  const int B = in_sizes[0] / NF;  // 8192
  const size_t need = (size_t)(NF * DE * WREC + NF * 32) * sizeof(float);  // ~1.1 MB

  if (ws_size >= need) {
    float* W   = (float*)d_ws;
    float* INV = W + (size_t)NF * DE * WREC;
    kan_prep<<<(NF * DE + 255) / 256, 256, 0, stream>>>(grid, bw, sw, ss, fc, fb, W, INV);
    dim3 gf(NF, (unsigned)((B + 255) / 256));
    kan_fused<<<gf, 256, 0, stream>>>(x, grid, INV, W, out, B);
  } else {
    dim3 mg(NF, (unsigned)((B + 255) / 256));
    kan_mono<<<mg, 256, 0, stream>>>(x, grid, bw, sw, ss, fc, fb, out, B);
  }
}